// Round 12
// baseline (321.104 us; speedup 1.0000x reference)
//
#include <hip/hip_runtime.h>
#include <hip/hip_bf16.h>

#define BSZ 4
#define SEQ 48
#define DMODEL 256
#define NHEAD 2
#define HD 128
#define NLAYERS 2
#define DFF_C 2048
#define NQ_C 512
#define NV 1176                 /* valid spans per batch: 48*49/2 */
#define NTOT (BSZ * NV)         /* 4704 */
#define NKP 1216                /* key dim padded to 64 (19*64): VT stride */
#define NQP 1280                /* query rows padded to 128 (10*128): Opart/ML */
#define KSPLIT 5                /* key splits for flash-decoding */
#define FSPLIT 4                /* K splits for FFN2 */
#define OSPLIT 2                /* K splits for out-proj */
#define LDQK 512                /* Q,K row stride (V lives in VT) */
#define SCALE 0.088388347648318447f   /* 1/sqrt(128) */

typedef unsigned short u16;
typedef __attribute__((ext_vector_type(8))) short bf16x8;
typedef __attribute__((ext_vector_type(4))) float f32x4;

__device__ inline u16 f2b(float f) {
    __hip_bfloat16 h = __float2bfloat16(f);
    return *reinterpret_cast<u16*>(&h);
}
__device__ inline void storeval(float* p, float v) { *p = v; }
__device__ inline void storeval(u16* p, float v) { *p = f2b(v); }

// ---------------------------------------------------------------- weight casts + span max + VT-pad zero
// blocks [0,2560): cast fp32 weights -> bf16. blocks [2560,2752): span max.
// blocks [2752,2832): zero VT padding keys [NV,NKP) (flash stages them
// unconditionally; QKV epilogue only writes keys < NV).
__global__ __launch_bounds__(256) void castspan_kernel(
    const float* __restrict__ iw, const float* __restrict__ ow,
    const float* __restrict__ f1w, const float* __restrict__ f2w,
    u16* __restrict__ iwb, u16* __restrict__ owb,
    u16* __restrict__ f1wb, u16* __restrict__ f2wb,
    const float* __restrict__ enc, float* __restrict__ X,
    u16* __restrict__ Xb, u16* __restrict__ VT) {
    int bid = blockIdx.x;
    if (bid < 2560) {
        int i = bid * 256 + threadIdx.x;
        const float* src;
        u16* dst;
        int off;
        if (i < 98304)       { src = iw;  dst = iwb;  off = i; }
        else if (i < 131072) { src = ow;  dst = owb;  off = i - 98304; }
        else if (i < 393216) { src = f1w; dst = f1wb; off = i - 131072; }
        else                 { src = f2w; dst = f2wb; off = i - 393216; }
        float4 v = *(const float4*)(src + (size_t)off * 4);
        *(ushort4*)(dst + (size_t)off * 4) =
            make_ushort4(f2b(v.x), f2b(v.y), f2b(v.z), f2b(v.w));
    } else if (bid < 2752) {
        int sb = bid - 2560;
        int i = sb % SEQ, b = sb / SEQ, h = threadIdx.x;
        int tb = i * SEQ - (i * (i - 1)) / 2 - i;   // t = tb + j
        float run = -1e30f;
        for (int j = i; j < SEQ; ++j) {
            run = fmaxf(run, enc[((size_t)b * SEQ + j) * DMODEL + h]);
            size_t idx = ((size_t)b * NV + tb + j) * DMODEL + h;
            X[idx] = run;
            Xb[idx] = f2b(run);
        }
    } else {
        // zero VT[row][NV..NKP): 1024 rows (8 bh x 128 d) x 40 u16 = 20 u32
        int i = (bid - 2752) * 256 + threadIdx.x;   // < 20480
        int row = i / 20, off = i % 20;
        ((unsigned int*)VT)[(size_t)row * (NKP / 2) + (NV / 2) + off] = 0u;
    }
}

// ---------------------------------------------------------------- MFMA GEMM 64x64, BK=64
// C[n,p] = alpha*sum_{k in split}A[n,k]*W[p,k] + bias[p] (+Res) (+relu).
// splitRows != 0: each z-split writes its own slab C + z*splitRows*ldc.
// VOUT: column tiles p0 >= 2*DMODEL (the V part of QKV) are written
// TRANSPOSED into VTout[bh][d][key] (aligned ushort4 over 4 consecutive
// keys) instead of C.
template <typename OutT, bool RELU, bool VOUT>
__global__ __launch_bounds__(256) void mm_kernel(
    const u16* __restrict__ A, const u16* __restrict__ W,
    const float* __restrict__ bias, const float* __restrict__ Res,
    OutT* __restrict__ C, u16* __restrict__ VTout,
    int N, int K, int lda, int ldw, int ldc,
    float alpha, int WV, int KC, int splitRows) {
    __shared__ u16 As[64][72];
    __shared__ u16 Ws[64][72];
    const float4 fz = make_float4(0.f, 0.f, 0.f, 0.f);
    int ks = blockIdx.z;
    int kb = ks * KC, ke = min(K, kb + KC);
    if (splitRows) C += (size_t)ks * splitRows * ldc;
    int p0 = blockIdx.x * 64, n0 = blockIdx.y * 64;
    int tid = threadIdx.x, lane = tid & 63, w = tid >> 6;
    int col_l = lane & 15, quad = lane >> 4;
    f32x4 acc[4] = {};
    for (int k0 = kb; k0 < ke; k0 += 64) {
        int r = tid >> 2, seg = (tid & 3) * 16;
        {
            int gn = n0 + r;
            const u16* ap = A + (size_t)gn * lda + k0 + seg;
            float4 a0 = fz, a1 = fz;
            if (gn < N) { a0 = *(const float4*)ap; a1 = *(const float4*)(ap + 8); }
            *(float4*)&As[r][seg] = a0;
            *(float4*)&As[r][seg + 8] = a1;
        }
        {
            int gp = p0 + r;
            const u16* wp = W + (size_t)gp * ldw + k0 + seg;
            float4 w0 = fz, w1 = fz;
            if (gp < WV) { w0 = *(const float4*)wp; w1 = *(const float4*)(wp + 8); }
            *(float4*)&Ws[r][seg] = w0;
            *(float4*)&Ws[r][seg + 8] = w1;
        }
        __syncthreads();
        bf16x8 a0 = *(const bf16x8*)&As[w * 16 + col_l][quad * 8];
        bf16x8 a1 = *(const bf16x8*)&As[w * 16 + col_l][32 + quad * 8];
#pragma unroll
        for (int c = 0; c < 4; ++c) {
            bf16x8 b0 = *(const bf16x8*)&Ws[c * 16 + col_l][quad * 8];
            bf16x8 b1 = *(const bf16x8*)&Ws[c * 16 + col_l][32 + quad * 8];
            acc[c] = __builtin_amdgcn_mfma_f32_16x16x32_bf16(a0, b0, acc[c], 0, 0, 0);
            acc[c] = __builtin_amdgcn_mfma_f32_16x16x32_bf16(a1, b1, acc[c], 0, 0, 0);
        }
        __syncthreads();
    }
    int row0 = n0 + w * 16 + quad * 4;
#pragma unroll
    for (int c = 0; c < 4; ++c) {
        int col = p0 + c * 16 + col_l;
        float bv = bias ? bias[col] : 0.f;
        float vv[4];
#pragma unroll
        for (int reg = 0; reg < 4; ++reg) {
            int row = row0 + reg;
            float v = acc[c][reg] * alpha + bv;
            if (Res && row < N) v += Res[(size_t)row * ldc + col];
            if (RELU) v = fmaxf(v, 0.f);
            vv[reg] = v;
        }
        if (VOUT && col >= 2 * DMODEL) {
            // V tile -> VT[bh][d][key], 4 consecutive keys per lane.
            if (row0 < N) {
                int b = row0 / NV, t = row0 - b * NV;
                int d = col - 2 * DMODEL;
                *(ushort4*)(VTout + ((size_t)(b * 2 + (d >> 7)) * HD + (d & 127)) * NKP + t) =
                    make_ushort4(f2b(vv[0]), f2b(vv[1]), f2b(vv[2]), f2b(vv[3]));
            }
        } else {
#pragma unroll
            for (int reg = 0; reg < 4; ++reg)
                if (row0 + reg < N)
                    storeval(&C[(size_t)(row0 + reg) * ldc + col], vv[reg]);
        }
    }
}

// ---------------------------------------------------------------- MFMA GEMM 64 rows x 128 cols, BK=64
template <typename OutT, bool RELU>
__global__ __launch_bounds__(256) void mmw_kernel(
    const u16* __restrict__ A, const u16* __restrict__ W,
    const float* __restrict__ bias,
    OutT* __restrict__ C, int N, int K, int lda, int ldw, int ldc,
    int WV, int KC, int splitRows) {
    __shared__ u16 As[64][72];
    __shared__ u16 Ws[128][72];
    const float4 fz = make_float4(0.f, 0.f, 0.f, 0.f);
    int ks = blockIdx.z;
    int kb = ks * KC, ke = min(K, kb + KC);
    if (splitRows) C += (size_t)ks * splitRows * ldc;
    int p0 = blockIdx.x * 128, n0 = blockIdx.y * 64;
    int tid = threadIdx.x, lane = tid & 63, w = tid >> 6;
    int col_l = lane & 15, quad = lane >> 4;
    f32x4 acc[8] = {};
    for (int k0 = kb; k0 < ke; k0 += 64) {
        {   // A tile 64 x 64
            int r = tid >> 2, seg = (tid & 3) * 16;
            int gn = n0 + r;
            const u16* ap = A + (size_t)gn * lda + k0 + seg;
            float4 a0 = fz, a1 = fz;
            if (gn < N) { a0 = *(const float4*)ap; a1 = *(const float4*)(ap + 8); }
            *(float4*)&As[r][seg] = a0;
            *(float4*)&As[r][seg + 8] = a1;
        }
        {   // W tile 128 x 64
            int r2 = tid >> 1, seg2 = (tid & 1) * 32;
            int gp = p0 + r2;
            const u16* wp = W + (size_t)gp * ldw + k0 + seg2;
#pragma unroll
            for (int j = 0; j < 4; ++j) {
                float4 wv = fz;
                if (gp < WV) wv = *(const float4*)(wp + j * 8);
                *(float4*)&Ws[r2][seg2 + j * 8] = wv;
            }
        }
        __syncthreads();
        bf16x8 a0 = *(const bf16x8*)&As[w * 16 + col_l][quad * 8];
        bf16x8 a1 = *(const bf16x8*)&As[w * 16 + col_l][32 + quad * 8];
#pragma unroll
        for (int c = 0; c < 8; ++c) {
            bf16x8 b0 = *(const bf16x8*)&Ws[c * 16 + col_l][quad * 8];
            bf16x8 b1 = *(const bf16x8*)&Ws[c * 16 + col_l][32 + quad * 8];
            acc[c] = __builtin_amdgcn_mfma_f32_16x16x32_bf16(a0, b0, acc[c], 0, 0, 0);
            acc[c] = __builtin_amdgcn_mfma_f32_16x16x32_bf16(a1, b1, acc[c], 0, 0, 0);
        }
        __syncthreads();
    }
#pragma unroll
    for (int c = 0; c < 8; ++c) {
        int col = p0 + c * 16 + col_l;
        float bv = bias ? bias[col] : 0.f;
#pragma unroll
        for (int reg = 0; reg < 4; ++reg) {
            int row = n0 + w * 16 + quad * 4 + reg;
            if (row < N) {
                float v = acc[c][reg] + bv;
                if (RELU) v = fmaxf(v, 0.f);
                storeval(&C[(size_t)row * ldc + col], v);
            }
        }
    }
}

// ---------------------------------------------------------------- flash-decoding attention, QBLK=128
// grid (10 qtiles of 128, 8 bh, KSPLIT). Each wave owns TWO 16-row groups
// (g=0: rows q0+w*16.., g=1: rows q0+64+w*16..) processed sequentially per
// staged K/V tile — halves total K/V LDS staging vs QBLK=64. T13
// defer-rescale with per-lane threshold; l as per-lane partials reduced once.
__global__ __launch_bounds__(256) void flash_kernel(const u16* __restrict__ QKb,
                                                    const u16* __restrict__ VT,
                                                    float* __restrict__ Opart,
                                                    float* __restrict__ ML) {
    __shared__ u16 Ks[64][136];
    __shared__ u16 Vt[128][72];
    __shared__ u16 Ps[4][16][72];
    const float4 fz = make_float4(0.f, 0.f, 0.f, 0.f);
    int tid = threadIdx.x, lane = tid & 63, w = tid >> 6;
    int col_l = lane & 15, quad = lane >> 4;
    int bh = blockIdx.y, b = bh >> 1, h = bh & 1;
    int ks = blockIdx.z;
    int t0 = ks * 4, tcnt = min(4, 19 - t0);
    size_t rb = (size_t)b * NV;
    int q0 = blockIdx.x * 128;

    // Q fragments in registers for both groups
    float4 qv[2][4];
#pragma unroll
    for (int g = 0; g < 2; ++g) {
        int qrow = q0 + g * 64 + w * 16 + col_l;
        if (qrow < NV) {
            const u16* qp = QKb + (rb + qrow) * LDQK + h * HD + quad * 8;
#pragma unroll
            for (int kf = 0; kf < 4; ++kf) qv[g][kf] = *(const float4*)(qp + kf * 32);
        } else {
#pragma unroll
            for (int kf = 0; kf < 4; ++kf) qv[g][kf] = fz;
        }
    }

    f32x4 oacc[2][8] = {};
    float m_run[2][4], l_part[2][4];
#pragma unroll
    for (int g = 0; g < 2; ++g)
#pragma unroll
        for (int r = 0; r < 4; ++r) { m_run[g][r] = -1e30f; l_part[g][r] = 0.f; }

    for (int it = 0; it < tcnt; ++it) {
        int kt = (t0 + it) * 64;
        {   // stage K tile: 64 keys x 128 d (vectorized)
            int r = tid >> 2, seg = (tid & 3) * 32;
            int key = kt + r;
            const u16* kp = QKb + (rb + key) * LDQK + DMODEL + h * HD + seg;
#pragma unroll
            for (int t4 = 0; t4 < 4; ++t4) {
                float4 v = fz;
                if (key < NV) v = *(const float4*)(kp + t4 * 8);
                *(float4*)&Ks[r][seg + t4 * 8] = v;
            }
        }
        {   // stage V^T tile from VT: 128 d x 64 keys (vectorized)
            int d = tid >> 1, half = (tid & 1) * 32;
            const u16* vp = VT + ((size_t)bh * HD + d) * NKP + kt + half;
#pragma unroll
            for (int t4 = 0; t4 < 4; ++t4)
                *(float4*)&Vt[d][half + t4 * 8] = *(const float4*)(vp + t4 * 8);
        }
        __syncthreads();

        bool allvalid = (kt + 64 <= NV);
#pragma unroll
        for (int g = 0; g < 2; ++g) {
            // S = Q K^T : 16 q-rows x 64 keys per wave per group
            f32x4 s[4] = {};
#pragma unroll
            for (int c = 0; c < 4; ++c)
#pragma unroll
                for (int kf = 0; kf < 4; ++kf) {
                    bf16x8 kfr = *(const bf16x8*)&Ks[c * 16 + col_l][kf * 32 + quad * 8];
                    s[c] = __builtin_amdgcn_mfma_f32_16x16x32_bf16(
                        *(const bf16x8*)&qv[g][kf], kfr, s[c], 0, 0, 0);
                }

            float pv[4][4];
            if (allvalid) {
#pragma unroll
                for (int c = 0; c < 4; ++c)
#pragma unroll
                    for (int r = 0; r < 4; ++r)
                        pv[c][r] = s[c][r] * SCALE;
            } else {
#pragma unroll
                for (int c = 0; c < 4; ++c) {
                    bool kvalid = (kt + c * 16 + col_l) < NV;
#pragma unroll
                    for (int r = 0; r < 4; ++r)
                        pv[c][r] = kvalid ? s[c][r] * SCALE : -1e30f;
                }
            }

            // per-lane partial row max; wave-uniform defer-rescale decision
            float pm[4];
            int need = 0;
#pragma unroll
            for (int r = 0; r < 4; ++r) {
                pm[r] = fmaxf(fmaxf(pv[0][r], pv[1][r]), fmaxf(pv[2][r], pv[3][r]));
                need |= (pm[r] > m_run[g][r] + 8.f) ? 1 : 0;
            }
            if (__any(need)) {
#pragma unroll
                for (int r = 0; r < 4; ++r) {
                    float mx = pm[r];
#pragma unroll
                    for (int off = 1; off < 16; off <<= 1)
                        mx = fmaxf(mx, __shfl_xor(mx, off));
                    float mn = fmaxf(m_run[g][r], mx);
                    float al = __expf(m_run[g][r] - mn);
                    m_run[g][r] = mn;
                    l_part[g][r] *= al;
#pragma unroll
                    for (int ct = 0; ct < 8; ++ct) oacc[g][ct][r] *= al;
                }
            }
#pragma unroll
            for (int r = 0; r < 4; ++r) {
#pragma unroll
                for (int c = 0; c < 4; ++c) {
                    float pp = __expf(pv[c][r] - m_run[g][r]);
                    pv[c][r] = pp;
                    l_part[g][r] += pp;
                }
            }

            // P C-layout -> per-wave LDS -> A-layout (DS in-order per wave;
            // Ps reused across groups safely for the same reason)
#pragma unroll
            for (int c = 0; c < 4; ++c)
#pragma unroll
                for (int r = 0; r < 4; ++r)
                    Ps[w][quad * 4 + r][c * 16 + col_l] = f2b(pv[c][r]);
            bf16x8 pf0 = *(const bf16x8*)&Ps[w][col_l][quad * 8];
            bf16x8 pf1 = *(const bf16x8*)&Ps[w][col_l][32 + quad * 8];
#pragma unroll
            for (int ct = 0; ct < 8; ++ct) {
                bf16x8 v0 = *(const bf16x8*)&Vt[ct * 16 + col_l][quad * 8];
                bf16x8 v1 = *(const bf16x8*)&Vt[ct * 16 + col_l][32 + quad * 8];
                oacc[g][ct] = __builtin_amdgcn_mfma_f32_16x16x32_bf16(pf0, v0, oacc[g][ct], 0, 0, 0);
                oacc[g][ct] = __builtin_amdgcn_mfma_f32_16x16x32_bf16(pf1, v1, oacc[g][ct], 0, 0, 0);
            }
        }
        __syncthreads();
    }

    // final l reduction (once per block)
    size_t slab = (size_t)(ks * 8 + bh) * NQP;
#pragma unroll
    for (int g = 0; g < 2; ++g) {
        float l_run[4];
#pragma unroll
        for (int r = 0; r < 4; ++r) {
            float sum = l_part[g][r];
#pragma unroll
            for (int off = 1; off < 16; off <<= 1) sum += __shfl_xor(sum, off);
            l_run[r] = sum;
        }
        int rowbase = q0 + g * 64 + w * 16 + quad * 4;
#pragma unroll
        for (int ct = 0; ct < 8; ++ct)
#pragma unroll
            for (int r = 0; r < 4; ++r)
                Opart[(slab + rowbase + r) * HD + ct * 16 + col_l] = oacc[g][ct][r];
        if (col_l == 0) {
#pragma unroll
            for (int r = 0; r < 4; ++r) {
                ML[(slab + rowbase + r) * 2 + 0] = m_run[g][r];
                ML[(slab + rowbase + r) * 2 + 1] = l_run[r];
            }
        }
    }
}

// ---------------------------------------------------------------- combine splits
// grid (588, 8): block = 2 rows x 128 d.
__global__ __launch_bounds__(256) void comb_kernel(const float* __restrict__ Opart,
                                                   const float* __restrict__ ML,
                                                   u16* __restrict__ Obuf) {
    int bh = blockIdx.y, b = bh >> 1, h = bh & 1;
    int tid = threadIdx.x;
    int row = blockIdx.x * 2 + (tid >> 7);
    int d = tid & 127;
    if (row >= NV) return;
    float m[KSPLIT], l[KSPLIT];
#pragma unroll
    for (int i = 0; i < KSPLIT; ++i) {
        size_t mb = ((size_t)(i * 8 + bh) * NQP + row) * 2;
        m[i] = ML[mb];
        l[i] = ML[mb + 1];
    }
    float M = m[0];
#pragma unroll
    for (int i = 1; i < KSPLIT; ++i) M = fmaxf(M, m[i]);
    float wsum = 0.f, o = 0.f;
#pragma unroll
    for (int i = 0; i < KSPLIT; ++i) {
        float wi = __expf(m[i] - M);
        wsum += l[i] * wi;
        o += Opart[((size_t)(i * 8 + bh) * NQP + row) * HD + d] * wi;
    }
    Obuf[((size_t)b * NV + row) * DMODEL + h * HD + d] = f2b(o / wsum);
}

// ---------------------------------------------------------------- slab-reduce + bias + residual + LN, wave-per-row
template <int NSLAB>
__global__ __launch_bounds__(256) void redln_kernel(const float* __restrict__ Xres,
                                                    const float* __restrict__ P,
                                                    const float* __restrict__ cbias,
                                                    const float* __restrict__ w,
                                                    const float* __restrict__ bb,
                                                    float* __restrict__ Y,
                                                    u16* __restrict__ Yb) {
    int wv = threadIdx.x >> 6, lane = threadIdx.x & 63;
    int r = blockIdx.x * 4 + wv;
    size_t base = (size_t)r * DMODEL + lane * 4;
    float4 v = *(const float4*)(Xres + base);
    float4 c4 = *(const float4*)(cbias + lane * 4);
    v.x += c4.x; v.y += c4.y; v.z += c4.z; v.w += c4.w;
#pragma unroll
    for (int z = 0; z < NSLAB; ++z) {
        float4 p4 = *(const float4*)(P + (size_t)z * NTOT * DMODEL + base);
        v.x += p4.x; v.y += p4.y; v.z += p4.z; v.w += p4.w;
    }
    float s1 = v.x + v.y + v.z + v.w;
    float s2 = v.x * v.x + v.y * v.y + v.z * v.z + v.w * v.w;
#pragma unroll
    for (int off = 32; off > 0; off >>= 1) {
        s1 += __shfl_xor(s1, off);
        s2 += __shfl_xor(s2, off);
    }
    float mean = s1 * (1.f / DMODEL);
    float var = s2 * (1.f / DMODEL) - mean * mean;
    float rstd = rsqrtf(var + 1e-5f);
    float4 w4 = *(const float4*)(w + lane * 4);
    float4 b4 = *(const float4*)(bb + lane * 4);
    float o0 = (v.x - mean) * rstd * w4.x + b4.x;
    float o1 = (v.y - mean) * rstd * w4.y + b4.y;
    float o2 = (v.z - mean) * rstd * w4.z + b4.z;
    float o3 = (v.w - mean) * rstd * w4.w + b4.w;
    *(float4*)(Y + base) = make_float4(o0, o1, o2, o3);
    *(ushort4*)(Yb + base) = make_ushort4(f2b(o0), f2b(o1), f2b(o2), f2b(o3));
}

// ---------------------------------------------------------------- last layer: slab-reduce + LN2 + final LN + gather
__global__ __launch_bounds__(64) void gatherln2_kernel(const float* __restrict__ Xres,
                                                       const float* __restrict__ P,
                                                       const float* __restrict__ cbias,
                                                       const float* __restrict__ w2,
                                                       const float* __restrict__ b2,
                                                       const float* __restrict__ fw,
                                                       const float* __restrict__ fb,
                                                       const int* __restrict__ s1,
                                                       const int* __restrict__ e1,
                                                       const int* __restrict__ qb,
                                                       const int* __restrict__ s2,
                                                       const int* __restrict__ e2,
                                                       float* __restrict__ out) {
    int q = blockIdx.x, which = blockIdx.y, lane = threadIdx.x;
    int s = which ? s2[q] : s1[q];
    int e = which ? e2[q] : e1[q];
    int b = qb[q];
    int t = s * SEQ - (s * (s - 1)) / 2 + (e - s);
    if (t < 0) t = 0;
    if (t >= NV) t = NV - 1;
    size_t base = ((size_t)b * NV + t) * DMODEL + lane * 4;
    float4 v = *(const float4*)(Xres + base);
    float4 c4 = *(const float4*)(cbias + lane * 4);
    v.x += c4.x; v.y += c4.y; v.z += c4.z; v.w += c4.w;
#pragma unroll
    for (int z = 0; z < FSPLIT; ++z) {
        float4 p4 = *(const float4*)(P + (size_t)z * NTOT * DMODEL + base);
        v.x += p4.x; v.y += p4.y; v.z += p4.z; v.w += p4.w;
    }
    // LN2
    float s1v = v.x + v.y + v.z + v.w;
    float s2v = v.x * v.x + v.y * v.y + v.z * v.z + v.w * v.w;
#pragma unroll
    for (int off = 32; off > 0; off >>= 1) {
        s1v += __shfl_xor(s1v, off);
        s2v += __shfl_xor(s2v, off);
    }
    float mean = s1v * (1.f / DMODEL);
    float var = s2v * (1.f / DMODEL) - mean * mean;
    float rstd = rsqrtf(var + 1e-5f);
    float4 w4 = *(const float4*)(w2 + lane * 4);
    float4 b4 = *(const float4*)(b2 + lane * 4);
    float o0 = (v.x - mean) * rstd * w4.x + b4.x;
    float o1 = (v.y - mean) * rstd * w4.y + b4.y;
    float o2 = (v.z - mean) * rstd * w4.z + b4.z;
    float o3 = (v.w - mean) * rstd * w4.w + b4.w;
    // final LN
    float t1 = o0 + o1 + o2 + o3;
    float t2 = o0 * o0 + o1 * o1 + o2 * o2 + o3 * o3;
#pragma unroll
    for (int off = 32; off > 0; off >>= 1) {
        t1 += __shfl_xor(t1, off);
        t2 += __shfl_xor(t2, off);
    }
    float mean2 = t1 * (1.f / DMODEL);
    float var2 = t2 * (1.f / DMODEL) - mean2 * mean2;
    float rstd2 = rsqrtf(var2 + 1e-5f);
    float4 fw4 = *(const float4*)(fw + lane * 4);
    float4 fb4 = *(const float4*)(fb + lane * 4);
    float r0 = (o0 - mean2) * rstd2 * fw4.x + fb4.x;
    float r1 = (o1 - mean2) * rstd2 * fw4.y + fb4.y;
    float r2 = (o2 - mean2) * rstd2 * fw4.z + fb4.z;
    float r3 = (o3 - mean2) * rstd2 * fw4.w + fb4.w;
    *(float4*)(out + ((size_t)which * NQ_C + q) * DMODEL + lane * 4) =
        make_float4(r0, r1, r2, r3);
}

// ---------------------------------------------------------------- launch
extern "C" void kernel_launch(void* const* d_in, const int* in_sizes, int n_in,
                              void* d_out, int out_size, void* d_ws, size_t ws_size,
                              hipStream_t stream) {
    const float* enc = (const float*)d_in[0];
    const float* iw  = (const float*)d_in[1];
    const float* ib  = (const float*)d_in[2];
    const float* ow  = (const float*)d_in[3];
    const float* ob  = (const float*)d_in[4];
    const float* l1w = (const float*)d_in[5];
    const float* l1b = (const float*)d_in[6];
    const float* l2w = (const float*)d_in[7];
    const float* l2b = (const float*)d_in[8];
    const float* f1w = (const float*)d_in[9];
    const float* f1b = (const float*)d_in[10];
    const float* f2w = (const float*)d_in[11];
    const float* f2b_ = (const float*)d_in[12];
    const float* flw = (const float*)d_in[13];
    const float* flb = (const float*)d_in[14];
    const int* s1 = (const int*)d_in[15];
    const int* e1 = (const int*)d_in[16];
    const int* qb = (const int*)d_in[17];
    const int* s2 = (const int*)d_in[18];
    const int* e2 = (const int*)d_in[19];
    float* out = (float*)d_out;

    // ---------------- workspace layout (~72 MB) ----------------
    char* p = (char*)d_ws;
    float* X     = (float*)p;  p += (size_t)NTOT * DMODEL * 4;
    u16* Xb      = (u16*)p;    p += (size_t)NTOT * DMODEL * 2;
    u16* Obuf    = (u16*)p;    p += (size_t)NTOT * DMODEL * 2;
    u16* QKb     = (u16*)p;    p += (size_t)NTOT * LDQK * 2;
    u16* VT      = (u16*)p;    p += (size_t)8 * HD * NKP * 2;
    float* ML    = (float*)p;  p += (size_t)KSPLIT * 8 * NQP * 2 * 4;
    float* Opart = (float*)p;  p += (size_t)KSPLIT * 8 * NQP * HD * 4;
    float* Pbuf  = (float*)p;  p += (size_t)FSPLIT * NTOT * DMODEL * 4;
    u16* wb      = (u16*)p;
    u16* F1b     = (u16*)Opart;  // alias: FFN phase doesn't overlap attention
                                 // phase (NTOT*DFF*2 = 19.3MB <= 26.2MB)

    u16* iwb  = wb;
    u16* owb  = iwb + 2 * 3 * DMODEL * DMODEL;
    u16* f1wb = owb + 2 * DMODEL * DMODEL;
    u16* f2wb = f1wb + 2 * DFF_C * DMODEL;

    castspan_kernel<<<dim3(2832), 256, 0, stream>>>(iw, ow, f1w, f2w,
                                                    iwb, owb, f1wb, f2wb,
                                                    enc, X, Xb, VT);

    for (int l = 0; l < NLAYERS; ++l) {
        // QKV = Xb @ iw^T + ib: Q,K -> QKb (ld 512); V -> VT (transposed)
        mm_kernel<u16, false, true><<<dim3(12, 74, 1), 256, 0, stream>>>(
            Xb, iwb + (size_t)l * 3 * DMODEL * DMODEL, ib + (size_t)l * 3 * DMODEL,
            nullptr, QKb, VT, NTOT, DMODEL, DMODEL, DMODEL, LDQK, 1.f,
            3 * DMODEL, DMODEL, 0);
        // flash-decoding attention partials (QBLK=128) + combine
        flash_kernel<<<dim3(10, 8, KSPLIT), 256, 0, stream>>>(QKb, VT, Opart, ML);
        comb_kernel<<<dim3(588, 8), 256, 0, stream>>>(Opart, ML, Obuf);
        // Pbuf[z] = Obuf @ ow^T (split-K x2, non-atomic slabs)
        mm_kernel<float, false, false><<<dim3(4, 74, OSPLIT), 256, 0, stream>>>(
            Obuf, owb + (size_t)l * DMODEL * DMODEL, nullptr, nullptr, Pbuf,
            nullptr, NTOT, DMODEL, DMODEL, DMODEL, DMODEL, 1.f, DMODEL,
            DMODEL / OSPLIT, NTOT);
        // LN1( X + ob + sum_z Pbuf[z] ) -> X, Xb
        redln_kernel<OSPLIT><<<dim3(NTOT / 4), 256, 0, stream>>>(
            X, Pbuf, ob + (size_t)l * DMODEL,
            l1w + (size_t)l * DMODEL, l1b + (size_t)l * DMODEL, X, Xb);
        // F1 = relu(Xb @ f1w^T + f1b) -> bf16 (wide tile 64x128)
        mmw_kernel<u16, true><<<dim3(16, 74, 1), 256, 0, stream>>>(
            Xb, f1wb + (size_t)l * DFF_C * DMODEL, f1b + (size_t)l * DFF_C,
            F1b, NTOT, DMODEL, DMODEL, DMODEL, DFF_C, DFF_C, DMODEL, 0);
        // Pbuf[z] = F1 @ f2w^T (split-K x4, non-atomic slabs, wide tile)
        mmw_kernel<float, false><<<dim3(2, 74, FSPLIT), 256, 0, stream>>>(
            F1b, f2wb + (size_t)l * DMODEL * DFF_C, nullptr, Pbuf,
            NTOT, DFF_C, DFF_C, DFF_C, DMODEL, DMODEL, DFF_C / FSPLIT, NTOT);
        if (l < NLAYERS - 1) {
            // LN2( X + f2b + sum_z Pbuf[z] ) -> X, Xb
            redln_kernel<FSPLIT><<<dim3(NTOT / 4), 256, 0, stream>>>(
                X, Pbuf, f2b_ + (size_t)l * DMODEL,
                l2w + (size_t)l * DMODEL, l2b + (size_t)l * DMODEL, X, Xb);
        } else {
            // last layer: slab-reduce + LN2 + final LN + gather in one launch
            gatherln2_kernel<<<dim3(NQ_C, 2), 64, 0, stream>>>(
                X, Pbuf, f2b_ + (size_t)l * DMODEL,
                l2w + (size_t)l * DMODEL, l2b + (size_t)l * DMODEL,
                flw, flb, s1, e1, qb, s2, e2, out);
        }
    }
}

// Round 13
// 291.358 us; speedup vs baseline: 1.1021x; 1.1021x over previous
//
#include <hip/hip_runtime.h>
#include <hip/hip_bf16.h>

#define BSZ 4
#define SEQ 48
#define DMODEL 256
#define NHEAD 2
#define HD 128
#define NLAYERS 2
#define DFF_C 2048
#define NQ_C 512
#define NV 1176                 /* valid spans per batch: 48*49/2 */
#define NTOT (BSZ * NV)         /* 4704 */
#define NVP 1216                /* NV padded to 64 multiple (19*64) */
#define KSPLIT 5                /* key splits for flash-decoding */
#define FSPLIT 4                /* K splits for FFN2 */
#define OSPLIT 2                /* K splits for out-proj */
#define LDQK 512                /* Q,K row stride (V lives in VT) */
#define SCALE 0.088388347648318447f   /* 1/sqrt(128) */

typedef unsigned short u16;
typedef __attribute__((ext_vector_type(8))) short bf16x8;
typedef __attribute__((ext_vector_type(4))) float f32x4;

__device__ inline u16 f2b(float f) {
    __hip_bfloat16 h = __float2bfloat16(f);
    return *reinterpret_cast<u16*>(&h);
}
__device__ inline void storeval(float* p, float v) { *p = v; }
__device__ inline void storeval(u16* p, float v) { *p = f2b(v); }

// ---------------------------------------------------------------- weight casts + span max + VT-pad zero
// blocks [0,2560): cast fp32 weights -> bf16. blocks [2560,2752): span max.
// blocks [2752,2832): zero VT padding keys [NV,NVP) (flash stages them
// unconditionally; QKV epilogue only writes keys < NV).
__global__ __launch_bounds__(256) void castspan_kernel(
    const float* __restrict__ iw, const float* __restrict__ ow,
    const float* __restrict__ f1w, const float* __restrict__ f2w,
    u16* __restrict__ iwb, u16* __restrict__ owb,
    u16* __restrict__ f1wb, u16* __restrict__ f2wb,
    const float* __restrict__ enc, float* __restrict__ X,
    u16* __restrict__ Xb, u16* __restrict__ VT) {
    int bid = blockIdx.x;
    if (bid < 2560) {
        int i = bid * 256 + threadIdx.x;
        const float* src;
        u16* dst;
        int off;
        if (i < 98304)       { src = iw;  dst = iwb;  off = i; }
        else if (i < 131072) { src = ow;  dst = owb;  off = i - 98304; }
        else if (i < 393216) { src = f1w; dst = f1wb; off = i - 131072; }
        else                 { src = f2w; dst = f2wb; off = i - 393216; }
        float4 v = *(const float4*)(src + (size_t)off * 4);
        *(ushort4*)(dst + (size_t)off * 4) =
            make_ushort4(f2b(v.x), f2b(v.y), f2b(v.z), f2b(v.w));
    } else if (bid < 2752) {
        int sb = bid - 2560;
        int i = sb % SEQ, b = sb / SEQ, h = threadIdx.x;
        int tb = i * SEQ - (i * (i - 1)) / 2 - i;   // t = tb + j
        float run = -1e30f;
        for (int j = i; j < SEQ; ++j) {
            run = fmaxf(run, enc[((size_t)b * SEQ + j) * DMODEL + h]);
            size_t idx = ((size_t)b * NV + tb + j) * DMODEL + h;
            X[idx] = run;
            Xb[idx] = f2b(run);
        }
    } else {
        // zero VT[row][NV..NVP): 1024 rows (8 bh x 128 d) x 40 u16 = 20 u32
        int i = (bid - 2752) * 256 + threadIdx.x;   // < 20480
        int row = i / 20, off = i % 20;
        ((unsigned int*)VT)[(size_t)row * (NVP / 2) + (NV / 2) + off] = 0u;
    }
}

// ---------------------------------------------------------------- MFMA GEMM 64x64, BK=64
// C[n,p] = alpha*sum_{k in split}A[n,k]*W[p,k] + bias[p] (+Res) (+relu).
// splitRows != 0: each z-split writes its own slab C + z*splitRows*ldc.
// VOUT: column tiles p0 >= 2*DMODEL (the V part of QKV) are written
// TRANSPOSED into VTout[bh][d][key] (aligned ushort4 over 4 consecutive
// keys) instead of C.
template <typename OutT, bool RELU, bool VOUT>
__global__ __launch_bounds__(256) void mm_kernel(
    const u16* __restrict__ A, const u16* __restrict__ W,
    const float* __restrict__ bias, const float* __restrict__ Res,
    OutT* __restrict__ C, u16* __restrict__ VTout,
    int N, int K, int lda, int ldw, int ldc,
    float alpha, int WV, int KC, int splitRows) {
    __shared__ u16 As[64][72];
    __shared__ u16 Ws[64][72];
    const float4 fz = make_float4(0.f, 0.f, 0.f, 0.f);
    int ks = blockIdx.z;
    int kb = ks * KC, ke = min(K, kb + KC);
    if (splitRows) C += (size_t)ks * splitRows * ldc;
    int p0 = blockIdx.x * 64, n0 = blockIdx.y * 64;
    int tid = threadIdx.x, lane = tid & 63, w = tid >> 6;
    int col_l = lane & 15, quad = lane >> 4;
    f32x4 acc[4] = {};
    for (int k0 = kb; k0 < ke; k0 += 64) {
        int r = tid >> 2, seg = (tid & 3) * 16;
        {
            int gn = n0 + r;
            const u16* ap = A + (size_t)gn * lda + k0 + seg;
            float4 a0 = fz, a1 = fz;
            if (gn < N) { a0 = *(const float4*)ap; a1 = *(const float4*)(ap + 8); }
            *(float4*)&As[r][seg] = a0;
            *(float4*)&As[r][seg + 8] = a1;
        }
        {
            int gp = p0 + r;
            const u16* wp = W + (size_t)gp * ldw + k0 + seg;
            float4 w0 = fz, w1 = fz;
            if (gp < WV) { w0 = *(const float4*)wp; w1 = *(const float4*)(wp + 8); }
            *(float4*)&Ws[r][seg] = w0;
            *(float4*)&Ws[r][seg + 8] = w1;
        }
        __syncthreads();
        bf16x8 a0 = *(const bf16x8*)&As[w * 16 + col_l][quad * 8];
        bf16x8 a1 = *(const bf16x8*)&As[w * 16 + col_l][32 + quad * 8];
#pragma unroll
        for (int c = 0; c < 4; ++c) {
            bf16x8 b0 = *(const bf16x8*)&Ws[c * 16 + col_l][quad * 8];
            bf16x8 b1 = *(const bf16x8*)&Ws[c * 16 + col_l][32 + quad * 8];
            acc[c] = __builtin_amdgcn_mfma_f32_16x16x32_bf16(a0, b0, acc[c], 0, 0, 0);
            acc[c] = __builtin_amdgcn_mfma_f32_16x16x32_bf16(a1, b1, acc[c], 0, 0, 0);
        }
        __syncthreads();
    }
    int row0 = n0 + w * 16 + quad * 4;
#pragma unroll
    for (int c = 0; c < 4; ++c) {
        int col = p0 + c * 16 + col_l;
        float bv = bias ? bias[col] : 0.f;
        float vv[4];
#pragma unroll
        for (int reg = 0; reg < 4; ++reg) {
            int row = row0 + reg;
            float v = acc[c][reg] * alpha + bv;
            if (Res && row < N) v += Res[(size_t)row * ldc + col];
            if (RELU) v = fmaxf(v, 0.f);
            vv[reg] = v;
        }
        if (VOUT && col >= 2 * DMODEL) {
            // V tile -> VT[bh][d][key], 4 consecutive keys per lane.
            if (row0 < N) {
                int b = row0 / NV, t = row0 - b * NV;
                int d = col - 2 * DMODEL;
                *(ushort4*)(VTout + ((size_t)(b * 2 + (d >> 7)) * HD + (d & 127)) * NVP + t) =
                    make_ushort4(f2b(vv[0]), f2b(vv[1]), f2b(vv[2]), f2b(vv[3]));
            }
        } else {
#pragma unroll
            for (int reg = 0; reg < 4; ++reg)
                if (row0 + reg < N)
                    storeval(&C[(size_t)(row0 + reg) * ldc + col], vv[reg]);
        }
    }
}

// ---------------------------------------------------------------- MFMA GEMM 64 rows x 128 cols, BK=64
template <typename OutT, bool RELU>
__global__ __launch_bounds__(256) void mmw_kernel(
    const u16* __restrict__ A, const u16* __restrict__ W,
    const float* __restrict__ bias,
    OutT* __restrict__ C, int N, int K, int lda, int ldw, int ldc,
    int WV, int KC, int splitRows) {
    __shared__ u16 As[64][72];
    __shared__ u16 Ws[128][72];
    const float4 fz = make_float4(0.f, 0.f, 0.f, 0.f);
    int ks = blockIdx.z;
    int kb = ks * KC, ke = min(K, kb + KC);
    if (splitRows) C += (size_t)ks * splitRows * ldc;
    int p0 = blockIdx.x * 128, n0 = blockIdx.y * 64;
    int tid = threadIdx.x, lane = tid & 63, w = tid >> 6;
    int col_l = lane & 15, quad = lane >> 4;
    f32x4 acc[8] = {};
    for (int k0 = kb; k0 < ke; k0 += 64) {
        {   // A tile 64 x 64
            int r = tid >> 2, seg = (tid & 3) * 16;
            int gn = n0 + r;
            const u16* ap = A + (size_t)gn * lda + k0 + seg;
            float4 a0 = fz, a1 = fz;
            if (gn < N) { a0 = *(const float4*)ap; a1 = *(const float4*)(ap + 8); }
            *(float4*)&As[r][seg] = a0;
            *(float4*)&As[r][seg + 8] = a1;
        }
        {   // W tile 128 x 64
            int r2 = tid >> 1, seg2 = (tid & 1) * 32;
            int gp = p0 + r2;
            const u16* wp = W + (size_t)gp * ldw + k0 + seg2;
#pragma unroll
            for (int j = 0; j < 4; ++j) {
                float4 wv = fz;
                if (gp < WV) wv = *(const float4*)(wp + j * 8);
                *(float4*)&Ws[r2][seg2 + j * 8] = wv;
            }
        }
        __syncthreads();
        bf16x8 a0 = *(const bf16x8*)&As[w * 16 + col_l][quad * 8];
        bf16x8 a1 = *(const bf16x8*)&As[w * 16 + col_l][32 + quad * 8];
#pragma unroll
        for (int c = 0; c < 8; ++c) {
            bf16x8 b0 = *(const bf16x8*)&Ws[c * 16 + col_l][quad * 8];
            bf16x8 b1 = *(const bf16x8*)&Ws[c * 16 + col_l][32 + quad * 8];
            acc[c] = __builtin_amdgcn_mfma_f32_16x16x32_bf16(a0, b0, acc[c], 0, 0, 0);
            acc[c] = __builtin_amdgcn_mfma_f32_16x16x32_bf16(a1, b1, acc[c], 0, 0, 0);
        }
        __syncthreads();
    }
#pragma unroll
    for (int c = 0; c < 8; ++c) {
        int col = p0 + c * 16 + col_l;
        float bv = bias ? bias[col] : 0.f;
#pragma unroll
        for (int reg = 0; reg < 4; ++reg) {
            int row = n0 + w * 16 + quad * 4 + reg;
            if (row < N) {
                float v = acc[c][reg] + bv;
                if (RELU) v = fmaxf(v, 0.f);
                storeval(&C[(size_t)row * ldc + col], v);
            }
        }
    }
}

// ---------------------------------------------------------------- flash-decoding attention
// grid (19 qtiles, 8 bh, KSPLIT). Each block: 64 queries x one key chunk.
// T13 defer-rescale with per-lane threshold check (no per-tile shuffle
// reduces in the fast path); l accumulated as per-lane partials and
// reduced once after the tile loop.
__global__ __launch_bounds__(256) void flash_kernel(const u16* __restrict__ QKb,
                                                    const u16* __restrict__ VT,
                                                    float* __restrict__ Opart,
                                                    float* __restrict__ ML) {
    __shared__ u16 Ks[64][136];
    __shared__ u16 Vt[128][72];
    __shared__ u16 Ps[4][16][72];
    const float4 fz = make_float4(0.f, 0.f, 0.f, 0.f);
    int tid = threadIdx.x, lane = tid & 63, w = tid >> 6;
    int col_l = lane & 15, quad = lane >> 4;
    int bh = blockIdx.y, b = bh >> 1, h = bh & 1;
    int ks = blockIdx.z;
    int t0 = ks * 4, tcnt = min(4, 19 - t0);
    size_t rb = (size_t)b * NV;
    int q0 = blockIdx.x * 64, wq0 = q0 + w * 16;

    // Q fragments in registers: A[m=col_l][k=quad*8+j], 4 k-frags (K=128)
    float4 qv[4];
    {
        int qrow = wq0 + col_l;
        if (qrow < NV) {
            const u16* qp = QKb + (rb + qrow) * LDQK + h * HD + quad * 8;
#pragma unroll
            for (int kf = 0; kf < 4; ++kf) qv[kf] = *(const float4*)(qp + kf * 32);
        } else {
#pragma unroll
            for (int kf = 0; kf < 4; ++kf) qv[kf] = fz;
        }
    }

    f32x4 oacc[8] = {};
    float m_run[4], l_part[4];
#pragma unroll
    for (int r = 0; r < 4; ++r) { m_run[r] = -1e30f; l_part[r] = 0.f; }

    for (int it = 0; it < tcnt; ++it) {
        int kt = (t0 + it) * 64;
        {   // stage K tile: 64 keys x 128 d (vectorized)
            int r = tid >> 2, seg = (tid & 3) * 32;
            int key = kt + r;
            const u16* kp = QKb + (rb + key) * LDQK + DMODEL + h * HD + seg;
#pragma unroll
            for (int t4 = 0; t4 < 4; ++t4) {
                float4 v = fz;
                if (key < NV) v = *(const float4*)(kp + t4 * 8);
                *(float4*)&Ks[r][seg + t4 * 8] = v;
            }
        }
        {   // stage V^T tile from VT: 128 d x 64 keys (vectorized)
            int d = tid >> 1, half = (tid & 1) * 32;
            const u16* vp = VT + ((size_t)bh * HD + d) * NVP + kt + half;
#pragma unroll
            for (int t4 = 0; t4 < 4; ++t4)
                *(float4*)&Vt[d][half + t4 * 8] = *(const float4*)(vp + t4 * 8);
        }
        __syncthreads();

        // S = Q K^T : 16 q-rows x 64 keys per wave
        f32x4 s[4] = {};
#pragma unroll
        for (int c = 0; c < 4; ++c)
#pragma unroll
            for (int kf = 0; kf < 4; ++kf) {
                bf16x8 kfr = *(const bf16x8*)&Ks[c * 16 + col_l][kf * 32 + quad * 8];
                s[c] = __builtin_amdgcn_mfma_f32_16x16x32_bf16(
                    *(const bf16x8*)&qv[kf], kfr, s[c], 0, 0, 0);
            }

        float pv[4][4];
        if (kt + 64 <= NV) {   // all keys valid (every tile but the last)
#pragma unroll
            for (int c = 0; c < 4; ++c)
#pragma unroll
                for (int r = 0; r < 4; ++r)
                    pv[c][r] = s[c][r] * SCALE;
        } else {
#pragma unroll
            for (int c = 0; c < 4; ++c) {
                bool kvalid = (kt + c * 16 + col_l) < NV;
#pragma unroll
                for (int r = 0; r < 4; ++r)
                    pv[c][r] = kvalid ? s[c][r] * SCALE : -1e30f;
            }
        }

        // per-lane partial row max; wave-uniform defer-rescale decision.
        // (wave max > thr  <=>  some lane's partial max > thr)
        float pm[4];
        int need = 0;
#pragma unroll
        for (int r = 0; r < 4; ++r) {
            pm[r] = fmaxf(fmaxf(pv[0][r], pv[1][r]), fmaxf(pv[2][r], pv[3][r]));
            need |= (pm[r] > m_run[r] + 8.f) ? 1 : 0;
        }
        if (__any(need)) {
#pragma unroll
            for (int r = 0; r < 4; ++r) {
                float mx = pm[r];
#pragma unroll
                for (int off = 1; off < 16; off <<= 1)
                    mx = fmaxf(mx, __shfl_xor(mx, off));
                float mn = fmaxf(m_run[r], mx);
                float al = __expf(m_run[r] - mn);
                m_run[r] = mn;
                l_part[r] *= al;
#pragma unroll
                for (int ct = 0; ct < 8; ++ct) oacc[ct][r] *= al;
            }
        }
#pragma unroll
        for (int r = 0; r < 4; ++r) {
#pragma unroll
            for (int c = 0; c < 4; ++c) {
                float pp = __expf(pv[c][r] - m_run[r]);
                pv[c][r] = pp;
                l_part[r] += pp;
            }
        }

        // P C-layout -> per-wave LDS -> A-layout (DS in-order per wave, no barrier)
#pragma unroll
        for (int c = 0; c < 4; ++c)
#pragma unroll
            for (int r = 0; r < 4; ++r)
                Ps[w][quad * 4 + r][c * 16 + col_l] = f2b(pv[c][r]);
        bf16x8 pf0 = *(const bf16x8*)&Ps[w][col_l][quad * 8];
        bf16x8 pf1 = *(const bf16x8*)&Ps[w][col_l][32 + quad * 8];
#pragma unroll
        for (int ct = 0; ct < 8; ++ct) {
            bf16x8 v0 = *(const bf16x8*)&Vt[ct * 16 + col_l][quad * 8];
            bf16x8 v1 = *(const bf16x8*)&Vt[ct * 16 + col_l][32 + quad * 8];
            oacc[ct] = __builtin_amdgcn_mfma_f32_16x16x32_bf16(pf0, v0, oacc[ct], 0, 0, 0);
            oacc[ct] = __builtin_amdgcn_mfma_f32_16x16x32_bf16(pf1, v1, oacc[ct], 0, 0, 0);
        }
        __syncthreads();
    }

    // final l reduction (once per block, was once per tile)
    float l_run[4];
#pragma unroll
    for (int r = 0; r < 4; ++r) {
        float sum = l_part[r];
#pragma unroll
        for (int off = 1; off < 16; off <<= 1) sum += __shfl_xor(sum, off);
        l_run[r] = sum;
    }

    // store unnormalized partials
    size_t slab = (size_t)(ks * 8 + bh) * NVP;
#pragma unroll
    for (int ct = 0; ct < 8; ++ct)
#pragma unroll
        for (int r = 0; r < 4; ++r) {
            int row = wq0 + quad * 4 + r;
            Opart[(slab + row) * HD + ct * 16 + col_l] = oacc[ct][r];
        }
    if (col_l == 0) {
#pragma unroll
        for (int r = 0; r < 4; ++r) {
            int row = wq0 + quad * 4 + r;
            ML[(slab + row) * 2 + 0] = m_run[r];
            ML[(slab + row) * 2 + 1] = l_run[r];
        }
    }
}

// ---------------------------------------------------------------- combine splits
// grid (588, 8): block = 2 rows x 128 d.
__global__ __launch_bounds__(256) void comb_kernel(const float* __restrict__ Opart,
                                                   const float* __restrict__ ML,
                                                   u16* __restrict__ Obuf) {
    int bh = blockIdx.y, b = bh >> 1, h = bh & 1;
    int tid = threadIdx.x;
    int row = blockIdx.x * 2 + (tid >> 7);
    int d = tid & 127;
    if (row >= NV) return;
    float m[KSPLIT], l[KSPLIT];
#pragma unroll
    for (int i = 0; i < KSPLIT; ++i) {
        size_t mb = ((size_t)(i * 8 + bh) * NVP + row) * 2;
        m[i] = ML[mb];
        l[i] = ML[mb + 1];
    }
    float M = m[0];
#pragma unroll
    for (int i = 1; i < KSPLIT; ++i) M = fmaxf(M, m[i]);
    float wsum = 0.f, o = 0.f;
#pragma unroll
    for (int i = 0; i < KSPLIT; ++i) {
        float wi = __expf(m[i] - M);
        wsum += l[i] * wi;
        o += Opart[((size_t)(i * 8 + bh) * NVP + row) * HD + d] * wi;
    }
    Obuf[((size_t)b * NV + row) * DMODEL + h * HD + d] = f2b(o / wsum);
}

// ---------------------------------------------------------------- slab-reduce + bias + residual + LN, wave-per-row
template <int NSLAB>
__global__ __launch_bounds__(256) void redln_kernel(const float* __restrict__ Xres,
                                                    const float* __restrict__ P,
                                                    const float* __restrict__ cbias,
                                                    const float* __restrict__ w,
                                                    const float* __restrict__ bb,
                                                    float* __restrict__ Y,
                                                    u16* __restrict__ Yb) {
    int wv = threadIdx.x >> 6, lane = threadIdx.x & 63;
    int r = blockIdx.x * 4 + wv;
    size_t base = (size_t)r * DMODEL + lane * 4;
    float4 v = *(const float4*)(Xres + base);
    float4 c4 = *(const float4*)(cbias + lane * 4);
    v.x += c4.x; v.y += c4.y; v.z += c4.z; v.w += c4.w;
#pragma unroll
    for (int z = 0; z < NSLAB; ++z) {
        float4 p4 = *(const float4*)(P + (size_t)z * NTOT * DMODEL + base);
        v.x += p4.x; v.y += p4.y; v.z += p4.z; v.w += p4.w;
    }
    float s1 = v.x + v.y + v.z + v.w;
    float s2 = v.x * v.x + v.y * v.y + v.z * v.z + v.w * v.w;
#pragma unroll
    for (int off = 32; off > 0; off >>= 1) {
        s1 += __shfl_xor(s1, off);
        s2 += __shfl_xor(s2, off);
    }
    float mean = s1 * (1.f / DMODEL);
    float var = s2 * (1.f / DMODEL) - mean * mean;
    float rstd = rsqrtf(var + 1e-5f);
    float4 w4 = *(const float4*)(w + lane * 4);
    float4 b4 = *(const float4*)(bb + lane * 4);
    float o0 = (v.x - mean) * rstd * w4.x + b4.x;
    float o1 = (v.y - mean) * rstd * w4.y + b4.y;
    float o2 = (v.z - mean) * rstd * w4.z + b4.z;
    float o3 = (v.w - mean) * rstd * w4.w + b4.w;
    *(float4*)(Y + base) = make_float4(o0, o1, o2, o3);
    *(ushort4*)(Yb + base) = make_ushort4(f2b(o0), f2b(o1), f2b(o2), f2b(o3));
}

// ---------------------------------------------------------------- last layer: slab-reduce + LN2 + final LN + gather
__global__ __launch_bounds__(64) void gatherln2_kernel(const float* __restrict__ Xres,
                                                       const float* __restrict__ P,
                                                       const float* __restrict__ cbias,
                                                       const float* __restrict__ w2,
                                                       const float* __restrict__ b2,
                                                       const float* __restrict__ fw,
                                                       const float* __restrict__ fb,
                                                       const int* __restrict__ s1,
                                                       const int* __restrict__ e1,
                                                       const int* __restrict__ qb,
                                                       const int* __restrict__ s2,
                                                       const int* __restrict__ e2,
                                                       float* __restrict__ out) {
    int q = blockIdx.x, which = blockIdx.y, lane = threadIdx.x;
    int s = which ? s2[q] : s1[q];
    int e = which ? e2[q] : e1[q];
    int b = qb[q];
    int t = s * SEQ - (s * (s - 1)) / 2 + (e - s);
    if (t < 0) t = 0;
    if (t >= NV) t = NV - 1;
    size_t base = ((size_t)b * NV + t) * DMODEL + lane * 4;
    float4 v = *(const float4*)(Xres + base);
    float4 c4 = *(const float4*)(cbias + lane * 4);
    v.x += c4.x; v.y += c4.y; v.z += c4.z; v.w += c4.w;
#pragma unroll
    for (int z = 0; z < FSPLIT; ++z) {
        float4 p4 = *(const float4*)(P + (size_t)z * NTOT * DMODEL + base);
        v.x += p4.x; v.y += p4.y; v.z += p4.z; v.w += p4.w;
    }
    // LN2
    float s1v = v.x + v.y + v.z + v.w;
    float s2v = v.x * v.x + v.y * v.y + v.z * v.z + v.w * v.w;
#pragma unroll
    for (int off = 32; off > 0; off >>= 1) {
        s1v += __shfl_xor(s1v, off);
        s2v += __shfl_xor(s2v, off);
    }
    float mean = s1v * (1.f / DMODEL);
    float var = s2v * (1.f / DMODEL) - mean * mean;
    float rstd = rsqrtf(var + 1e-5f);
    float4 w4 = *(const float4*)(w2 + lane * 4);
    float4 b4 = *(const float4*)(b2 + lane * 4);
    float o0 = (v.x - mean) * rstd * w4.x + b4.x;
    float o1 = (v.y - mean) * rstd * w4.y + b4.y;
    float o2 = (v.z - mean) * rstd * w4.z + b4.z;
    float o3 = (v.w - mean) * rstd * w4.w + b4.w;
    // final LN
    float t1 = o0 + o1 + o2 + o3;
    float t2 = o0 * o0 + o1 * o1 + o2 * o2 + o3 * o3;
#pragma unroll
    for (int off = 32; off > 0; off >>= 1) {
        t1 += __shfl_xor(t1, off);
        t2 += __shfl_xor(t2, off);
    }
    float mean2 = t1 * (1.f / DMODEL);
    float var2 = t2 * (1.f / DMODEL) - mean2 * mean2;
    float rstd2 = rsqrtf(var2 + 1e-5f);
    float4 fw4 = *(const float4*)(fw + lane * 4);
    float4 fb4 = *(const float4*)(fb + lane * 4);
    float r0 = (o0 - mean2) * rstd2 * fw4.x + fb4.x;
    float r1 = (o1 - mean2) * rstd2 * fw4.y + fb4.y;
    float r2 = (o2 - mean2) * rstd2 * fw4.z + fb4.z;
    float r3 = (o3 - mean2) * rstd2 * fw4.w + fb4.w;
    *(float4*)(out + ((size_t)which * NQ_C + q) * DMODEL + lane * 4) =
        make_float4(r0, r1, r2, r3);
}

// ---------------------------------------------------------------- launch
extern "C" void kernel_launch(void* const* d_in, const int* in_sizes, int n_in,
                              void* d_out, int out_size, void* d_ws, size_t ws_size,
                              hipStream_t stream) {
    const float* enc = (const float*)d_in[0];
    const float* iw  = (const float*)d_in[1];
    const float* ib  = (const float*)d_in[2];
    const float* ow  = (const float*)d_in[3];
    const float* ob  = (const float*)d_in[4];
    const float* l1w = (const float*)d_in[5];
    const float* l1b = (const float*)d_in[6];
    const float* l2w = (const float*)d_in[7];
    const float* l2b = (const float*)d_in[8];
    const float* f1w = (const float*)d_in[9];
    const float* f1b = (const float*)d_in[10];
    const float* f2w = (const float*)d_in[11];
    const float* f2b_ = (const float*)d_in[12];
    const float* flw = (const float*)d_in[13];
    const float* flb = (const float*)d_in[14];
    const int* s1 = (const int*)d_in[15];
    const int* e1 = (const int*)d_in[16];
    const int* qb = (const int*)d_in[17];
    const int* s2 = (const int*)d_in[18];
    const int* e2 = (const int*)d_in[19];
    float* out = (float*)d_out;

    // ---------------- workspace layout (~70 MB) ----------------
    char* p = (char*)d_ws;
    float* X     = (float*)p;  p += (size_t)NTOT * DMODEL * 4;
    u16* Xb      = (u16*)p;    p += (size_t)NTOT * DMODEL * 2;
    u16* Obuf    = (u16*)p;    p += (size_t)NTOT * DMODEL * 2;
    u16* QKb     = (u16*)p;    p += (size_t)NTOT * LDQK * 2;
    u16* VT      = (u16*)p;    p += (size_t)8 * HD * NVP * 2;
    float* ML    = (float*)p;  p += (size_t)KSPLIT * 8 * NVP * 2 * 4;
    float* Opart = (float*)p;  p += (size_t)KSPLIT * 8 * NVP * HD * 4;
    float* Pbuf  = (float*)p;  p += (size_t)FSPLIT * NTOT * DMODEL * 4;
    u16* wb      = (u16*)p;
    u16* F1b     = (u16*)Opart;  // alias: FFN phase doesn't overlap attention phase

    u16* iwb  = wb;
    u16* owb  = iwb + 2 * 3 * DMODEL * DMODEL;
    u16* f1wb = owb + 2 * DMODEL * DMODEL;
    u16* f2wb = f1wb + 2 * DFF_C * DMODEL;

    castspan_kernel<<<dim3(2832), 256, 0, stream>>>(iw, ow, f1w, f2w,
                                                    iwb, owb, f1wb, f2wb,
                                                    enc, X, Xb, VT);

    for (int l = 0; l < NLAYERS; ++l) {
        // QKV = Xb @ iw^T + ib: Q,K -> QKb (ld 512); V -> VT (transposed)
        mm_kernel<u16, false, true><<<dim3(12, 74, 1), 256, 0, stream>>>(
            Xb, iwb + (size_t)l * 3 * DMODEL * DMODEL, ib + (size_t)l * 3 * DMODEL,
            nullptr, QKb, VT, NTOT, DMODEL, DMODEL, DMODEL, LDQK, 1.f,
            3 * DMODEL, DMODEL, 0);
        // flash-decoding attention partials + combine
        flash_kernel<<<dim3(19, 8, KSPLIT), 256, 0, stream>>>(QKb, VT, Opart, ML);
        comb_kernel<<<dim3(588, 8), 256, 0, stream>>>(Opart, ML, Obuf);
        // Pbuf[z] = Obuf @ ow^T (split-K x2, non-atomic slabs)
        mm_kernel<float, false, false><<<dim3(4, 74, OSPLIT), 256, 0, stream>>>(
            Obuf, owb + (size_t)l * DMODEL * DMODEL, nullptr, nullptr, Pbuf,
            nullptr, NTOT, DMODEL, DMODEL, DMODEL, DMODEL, 1.f, DMODEL,
            DMODEL / OSPLIT, NTOT);
        // LN1( X + ob + sum_z Pbuf[z] ) -> X, Xb
        redln_kernel<OSPLIT><<<dim3(NTOT / 4), 256, 0, stream>>>(
            X, Pbuf, ob + (size_t)l * DMODEL,
            l1w + (size_t)l * DMODEL, l1b + (size_t)l * DMODEL, X, Xb);
        // F1 = relu(Xb @ f1w^T + f1b) -> bf16 (wide tile 64x128)
        mmw_kernel<u16, true><<<dim3(16, 74, 1), 256, 0, stream>>>(
            Xb, f1wb + (size_t)l * DFF_C * DMODEL, f1b + (size_t)l * DFF_C,
            F1b, NTOT, DMODEL, DMODEL, DMODEL, DFF_C, DFF_C, DMODEL, 0);
        // Pbuf[z] = F1 @ f2w^T (split-K x4, non-atomic slabs, wide tile)
        mmw_kernel<float, false><<<dim3(2, 74, FSPLIT), 256, 0, stream>>>(
            F1b, f2wb + (size_t)l * DMODEL * DFF_C, nullptr, Pbuf,
            NTOT, DFF_C, DFF_C, DFF_C, DMODEL, DMODEL, DFF_C / FSPLIT, NTOT);
        if (l < NLAYERS - 1) {
            // LN2( X + f2b + sum_z Pbuf[z] ) -> X, Xb
            redln_kernel<FSPLIT><<<dim3(NTOT / 4), 256, 0, stream>>>(
                X, Pbuf, f2b_ + (size_t)l * DMODEL,
                l2w + (size_t)l * DMODEL, l2b + (size_t)l * DMODEL, X, Xb);
        } else {
            // last layer: slab-reduce + LN2 + final LN + gather in one launch
            gatherln2_kernel<<<dim3(NQ_C, 2), 64, 0, stream>>>(
                X, Pbuf, f2b_ + (size_t)l * DMODEL,
                l2w + (size_t)l * DMODEL, l2b + (size_t)l * DMODEL,
                flw, flb, s1, e1, qb, s2, e2, out);
        }
    }
}